// Round 6
// baseline (1979.711 us; speedup 1.0000x reference)
//
#include <hip/hip_runtime.h>
#include <math.h>

#define NB 32
#define L  1024
#define CH 256                 // timesteps per chunk
#define NCH (L / CH)           // 4 chunks
#define RC (NB * CH)           // 8192 rows per chunk
#define DM 256
#define DI 512
#define DS 16
#define SCT 16                 // sub-chunk timesteps (scan)
#define NSC (CH / SCT)         // 16 sub-chunks
#define LOG2E 1.44269504f

typedef short short8 __attribute__((ext_vector_type(8)));
typedef float f32x4 __attribute__((ext_vector_type(4)));

// bf16 split helpers: x ~= hi + lo, both bf16 (rne). pair = hi | (lo<<16).
__device__ inline unsigned f2bf_u(float x) {
    unsigned u = __float_as_uint(x);
    return (u + 0x7fffu + ((u >> 16) & 1u)) >> 16;
}
__device__ inline unsigned packpair(float v) {
    unsigned h = f2bf_u(v);
    float hf = __uint_as_float(h << 16);
    unsigned l = f2bf_u(v - hf);
    return h | (l << 16);
}

// Layout: per-chunk activations use (t_local, b, feat): row r = t_local*32 + b.

// ---------------------------------------------------------------------------
// p1 (K=4) + bias + LayerNorm; emits bf16 hi/lo pairs for the MFMA in_proj.
// ---------------------------------------------------------------------------
__global__ __launch_bounds__(256) void k_p1_ln(
    const float* __restrict__ xseq, const float* __restrict__ w,
    const float* __restrict__ bias, const float* __restrict__ g,
    const float* __restrict__ bb, unsigned* __restrict__ out, int t0)
{
    int r  = blockIdx.x;
    int b  = r & 31;
    int tl = r >> 5;
    int m  = threadIdx.x;
    const float* xr = xseq + ((size_t)b * L + t0 + tl) * 4;
    float x0 = xr[0], x1 = xr[1], x2 = xr[2], x3 = xr[3];
    const float* wr = w + m * 4;
    float v = bias[m] + x0 * wr[0] + x1 * wr[1] + x2 * wr[2] + x3 * wr[3];

    __shared__ float s1[4], s2[4];
    float a = v, bq = v * v;
    for (int o = 32; o > 0; o >>= 1) { a += __shfl_down(a, o); bq += __shfl_down(bq, o); }
    int wid = m >> 6, lane = m & 63;
    if (lane == 0) { s1[wid] = a; s2[wid] = bq; }
    __syncthreads();
    if (m == 0) {
        s1[0] = s1[0] + s1[1] + s1[2] + s1[3];
        s2[0] = s2[0] + s2[1] + s2[2] + s2[3];
    }
    __syncthreads();
    float mu  = s1[0] * (1.f / 256.f);
    float var = s2[0] * (1.f / 256.f) - mu * mu;
    float o2 = (v - mu) * rsqrtf(var + 1e-5f) * g[m] + bb[m];
    out[(size_t)r * 256 + m] = packpair(o2);
}

// ---------------------------------------------------------------------------
// LayerNorm over 256; fp32 in, bf16-pair out.
// ---------------------------------------------------------------------------
__global__ __launch_bounds__(256) void k_ln(
    const float* __restrict__ in, const float* __restrict__ g,
    const float* __restrict__ bb, unsigned* __restrict__ out)
{
    int r = blockIdx.x;
    int m = threadIdx.x;
    float v = in[(size_t)r * 256 + m];

    __shared__ float s1[4], s2[4];
    float a = v, bq = v * v;
    for (int o = 32; o > 0; o >>= 1) { a += __shfl_down(a, o); bq += __shfl_down(bq, o); }
    int wid = m >> 6, lane = m & 63;
    if (lane == 0) { s1[wid] = a; s2[wid] = bq; }
    __syncthreads();
    if (m == 0) {
        s1[0] = s1[0] + s1[1] + s1[2] + s1[3];
        s2[0] = s2[0] + s2[1] + s2[2] + s2[3];
    }
    __syncthreads();
    float mu  = s1[0] * (1.f / 256.f);
    float var = s2[0] * (1.f / 256.f) - mu * mu;
    float o2 = (v - mu) * rsqrtf(var + 1e-5f) * g[m] + bb[m];
    out[(size_t)r * 256 + m] = packpair(o2);
}

__global__ __launch_bounds__(256) void k_wcvt(
    const float* __restrict__ w, unsigned* __restrict__ o, int n)
{
    int i = blockIdx.x * 256 + threadIdx.x;
    if (i < n) o[i] = packpair(w[i]);
}

// ---------------------------------------------------------------------------
// split-bf16 MFMA GEMM (3-term): C[M,N] = A[M,K]*W[N,K]^T (+bias).
// 128x128 tile, BK=32, 4 waves x 64x64 quadrant of 4x4 16x16x32 frags.
// ---------------------------------------------------------------------------
template <int OUTK, bool BIAS>
__global__ __launch_bounds__(256) void k_gmfma(
    const unsigned* __restrict__ Ap, int lda,
    const unsigned* __restrict__ Wp,
    const float* __restrict__ bias, void* __restrict__ Cv,
    int N, int K)
{
    __shared__ unsigned short Ah[128 * 40], Al[128 * 40];
    __shared__ unsigned short Wh[128 * 40], Wl[128 * 40];

    int tid = threadIdx.x;
    int wv = tid >> 6, ln = tid & 63;
    int wr = wv >> 1, wc = wv & 1;
    int m0 = blockIdx.x * 128, n0 = blockIdx.y * 128;
    int sr = tid >> 1, sk = (tid & 1) << 4;
    int frow = ln & 15, fk = (ln >> 4) << 3;

    f32x4 acc[4][4] = {};

    for (int k0 = 0; k0 < K; k0 += 32) {
        const unsigned* ap = Ap + (size_t)(m0 + sr) * lda + k0 + sk;
        const unsigned* wp = Wp + (size_t)(n0 + sr) * K + k0 + sk;
        uint4 qa[4], qw[4];
#pragma unroll
        for (int i = 0; i < 4; i++) qa[i] = *(const uint4*)(ap + i * 4);
#pragma unroll
        for (int i = 0; i < 4; i++) qw[i] = *(const uint4*)(wp + i * 4);

        __syncthreads();

        unsigned short th[16], tl[16];
#pragma unroll
        for (int i = 0; i < 4; i++) {
            th[i*4+0] = (unsigned short)qa[i].x; tl[i*4+0] = (unsigned short)(qa[i].x >> 16);
            th[i*4+1] = (unsigned short)qa[i].y; tl[i*4+1] = (unsigned short)(qa[i].y >> 16);
            th[i*4+2] = (unsigned short)qa[i].z; tl[i*4+2] = (unsigned short)(qa[i].z >> 16);
            th[i*4+3] = (unsigned short)qa[i].w; tl[i*4+3] = (unsigned short)(qa[i].w >> 16);
        }
        *(short8*)&Ah[sr * 40 + sk]     = *(short8*)&th[0];
        *(short8*)&Ah[sr * 40 + sk + 8] = *(short8*)&th[8];
        *(short8*)&Al[sr * 40 + sk]     = *(short8*)&tl[0];
        *(short8*)&Al[sr * 40 + sk + 8] = *(short8*)&tl[8];
#pragma unroll
        for (int i = 0; i < 4; i++) {
            th[i*4+0] = (unsigned short)qw[i].x; tl[i*4+0] = (unsigned short)(qw[i].x >> 16);
            th[i*4+1] = (unsigned short)qw[i].y; tl[i*4+1] = (unsigned short)(qw[i].y >> 16);
            th[i*4+2] = (unsigned short)qw[i].z; tl[i*4+2] = (unsigned short)(qw[i].z >> 16);
            th[i*4+3] = (unsigned short)qw[i].w; tl[i*4+3] = (unsigned short)(qw[i].w >> 16);
        }
        *(short8*)&Wh[sr * 40 + sk]     = *(short8*)&th[0];
        *(short8*)&Wh[sr * 40 + sk + 8] = *(short8*)&th[8];
        *(short8*)&Wl[sr * 40 + sk]     = *(short8*)&tl[0];
        *(short8*)&Wl[sr * 40 + sk + 8] = *(short8*)&tl[8];

        __syncthreads();

        short8 afh[4], afl[4], wfh[4], wfl[4];
#pragma unroll
        for (int g = 0; g < 4; g++) {
            int ra = (wr * 64 + g * 16 + frow) * 40 + fk;
            int rw = (wc * 64 + g * 16 + frow) * 40 + fk;
            afh[g] = *(const short8*)&Ah[ra];
            afl[g] = *(const short8*)&Al[ra];
            wfh[g] = *(const short8*)&Wh[rw];
            wfl[g] = *(const short8*)&Wl[rw];
        }
#pragma unroll
        for (int mg = 0; mg < 4; mg++)
#pragma unroll
            for (int ng = 0; ng < 4; ng++) {
                acc[mg][ng] = __builtin_amdgcn_mfma_f32_16x16x32_bf16(afh[mg], wfh[ng], acc[mg][ng], 0, 0, 0);
                acc[mg][ng] = __builtin_amdgcn_mfma_f32_16x16x32_bf16(afh[mg], wfl[ng], acc[mg][ng], 0, 0, 0);
                acc[mg][ng] = __builtin_amdgcn_mfma_f32_16x16x32_bf16(afl[mg], wfh[ng], acc[mg][ng], 0, 0, 0);
            }
    }

    // C layout: col=lane&15, row=(lane>>4)*4+reg  [verified m89]
#pragma unroll
    for (int ng = 0; ng < 4; ng++) {
        int col = n0 + wc * 64 + ng * 16 + frow;
        float bv = BIAS ? bias[col] : 0.f;
#pragma unroll
        for (int mg = 0; mg < 4; mg++)
#pragma unroll
            for (int r = 0; r < 4; r++) {
                int row = m0 + wr * 64 + mg * 16 + (ln >> 4) * 4 + r;
                float v = acc[mg][ng][r] + bv;
                if (OUTK == 0) ((float*)Cv)[(size_t)row * N + col] = v;
                else           ((unsigned*)Cv)[(size_t)row * N + col] = packpair(v);
            }
    }
}

// ---------------------------------------------------------------------------
// FUSED conv(k=4)+SiLU + xproj(48) + dt-proj(16)+softplus.
// One block = 8 consecutive rows (same timestep tl, 8 batches).
// grid = RC/8 = 1024.
// ---------------------------------------------------------------------------
__global__ __launch_bounds__(256) void k_cxd(
    const float* __restrict__ xz, const float* __restrict__ halo,
    const float* __restrict__ cw, const float* __restrict__ cb,
    const float* __restrict__ xpw,
    const float* __restrict__ dtw, const float* __restrict__ dtb,
    float* __restrict__ xc, float* __restrict__ dbc, float* __restrict__ dtf,
    int t0)
{
    __shared__ float xcs[8][512];
    __shared__ float part[48][4];
    __shared__ float dtr[8][16];

    int blk = blockIdx.x;
    int tid = threadIdx.x;
    int tl  = blk >> 2;           // same for all 8 rows
    int b0  = (blk & 3) * 8;

    // phase 1: conv + silu
    for (int e = 0; e < 16; e++) {
        int idx = e * 256 + tid;
        int rr = idx >> 9;
        int d  = idx & 511;
        int b  = b0 + rr;
        float4 wv = *(const float4*)(cw + d * 4);
        float wk[4] = { wv.x, wv.y, wv.z, wv.w };
        float acc = cb[d];
#pragma unroll
        for (int k = 0; k < 4; k++) {
            int tsl = tl - 3 + k;
            float v;
            if (tsl >= 0) v = xz[((size_t)tsl * 32 + b) * 1024 + d];
            else {
                int ts = t0 + tsl;
                v = (ts < 0) ? 0.f : halo[((size_t)(tsl + 3) * 32 + b) * 512 + d];
            }
            acc = fmaf(wk[k], v, acc);
        }
        float s = acc / (1.f + __expf(-acc));
        xcs[rr][d] = s;
        xc[((size_t)tl * 32 + b) * 512 + d] = s;
    }
    __syncthreads();

    // phase 2: xproj per row (192 threads: j=tid>>2 in [0,48), seg=tid&3)
    int j = tid >> 2, seg = tid & 3;
    for (int rr = 0; rr < 8; rr++) {
        if (tid < 192) {
            const float* wrow = xpw + (size_t)j * 512 + seg * 128;
            const float* xr = &xcs[rr][seg * 128];
            float acc = 0.f;
#pragma unroll 8
            for (int k = 0; k < 128; k += 4) {
                float4 wv = *(const float4*)(wrow + k);
                float4 xv = *(const float4*)(xr + k);
                acc = fmaf(wv.x, xv.x, acc);
                acc = fmaf(wv.y, xv.y, acc);
                acc = fmaf(wv.z, xv.z, acc);
                acc = fmaf(wv.w, xv.w, acc);
            }
            part[j][seg] = acc;
        }
        __syncthreads();
        if (tid < 48) {
            float s = part[tid][0] + part[tid][1] + part[tid][2] + part[tid][3];
            int r = tl * 32 + b0 + rr;
            dbc[(size_t)r * 48 + tid] = s;
            if (tid < 16) dtr[rr][tid] = s;
        }
        __syncthreads();
    }

    // phase 3: dt-proj + softplus
    for (int e = 0; e < 16; e++) {
        int idx = e * 256 + tid;
        int rr = idx >> 9;
        int d  = idx & 511;
        const float* w = dtw + d * 16;
        float s = dtb[d];
#pragma unroll
        for (int k = 0; k < 16; k += 4) {
            float4 wv = *(const float4*)(w + k);
            s = fmaf(wv.x, dtr[rr][k + 0], s);
            s = fmaf(wv.y, dtr[rr][k + 1], s);
            s = fmaf(wv.z, dtr[rr][k + 2], s);
            s = fmaf(wv.w, dtr[rr][k + 3], s);
        }
        s = (s > 20.f) ? s : log1pf(expf(s));
        dtf[((size_t)tl * 32 + b0 + rr) * 512 + d] = s;
    }
}

__global__ __launch_bounds__(256) void k_halo(
    const float* __restrict__ xz, float* __restrict__ halo)
{
    int idx = blockIdx.x * 256 + threadIdx.x;  // over 3*32*512
    int d = idx & 511;
    int b = (idx >> 9) & 31;
    int s = idx >> 14;
    halo[idx] = xz[(((size_t)(CH - 3 + s) * 32 + b) << 10) + d];
}

// ---------------------------------------------------------------------------
// scan pass A: local scan per sub-chunk (h=0). Writes ONLY hend + sumdt.
// grid: b(32) x half(2) x subchunk(16) = 1024 blocks.
// ---------------------------------------------------------------------------
__global__ __launch_bounds__(256) void k_scanA(
    const float* __restrict__ dtf, const float* __restrict__ xc,
    const float* __restrict__ dbc, const float* __restrict__ A_log,
    float* __restrict__ hend, float* __restrict__ sumdt)
{
    int bx = blockIdx.x;
    int b    = bx >> 5;
    int half = (bx >> 4) & 1;
    int c    = bx & 15;
    int d = (half << 8) + threadIdx.x;

    float A2[DS], h[DS];
#pragma unroll
    for (int s = 0; s < DS; s++) {
        A2[s] = -__expf(A_log[d * DS + s]) * LOG2E;
        h[s] = 0.f;
    }

    __shared__ float Bs[SCT][16];
    {
        int f = threadIdx.x;           // SCT*16 = 256 exactly
        int tt = f >> 4, jj = f & 15;
        Bs[tt][jj] = dbc[((size_t)(c * SCT + tt) * 32 + b) * 48 + 16 + jj];
    }
    __syncthreads();

    float cum = 0.f;
    for (int tt = 0; tt < SCT; tt++) {
        size_t idx = ((size_t)(c * SCT + tt) * 32 + b) * DI + d;
        float dt = dtf[idx];
        cum += dt;
        float dtx = dt * xc[idx];
#pragma unroll
        for (int s = 0; s < DS; s++) {
            float dA = exp2f(dt * A2[s]);
            h[s] = fmaf(dA, h[s], dtx * Bs[tt][s]);
        }
    }
    float* hp = hend + ((size_t)(c * 32 + b) * 512 + d) * DS;
#pragma unroll
    for (int s = 0; s < DS; s++) hp[s] = h[s];
    sumdt[((size_t)c * 32 + b) * 512 + d] = cum;
}

// ---------------------------------------------------------------------------
// scan pass B: carry across 16 sub-chunks; hend -> h_init, carry -> hs.
// ---------------------------------------------------------------------------
__global__ __launch_bounds__(256) void k_scanB(
    const float* __restrict__ sumdt, float* __restrict__ hend,
    const float* __restrict__ A_log, float* __restrict__ hs, int first)
{
    int id = blockIdx.x * 256 + threadIdx.x;   // 32*512*16 = 262144
    int s = id & 15;
    int d = (id >> 4) & 511;
    int b = id >> 13;
    float A2 = -__expf(A_log[d * DS + s]) * LOG2E;
    size_t hsi = ((size_t)(b << 9) + d) * DS + s;
    float hin = first ? 0.f : hs[hsi];
    for (int c = 0; c < NSC; c++) {
        size_t hi = ((size_t)(c * 32 + b) * 512 + d) * DS + s;
        float he = hend[hi];
        float sd = sumdt[((size_t)c * 32 + b) * 512 + d];
        hend[hi] = hin;
        hin = fmaf(exp2f(A2 * sd), hin, he);
    }
    hs[hsi] = hin;
}

// ---------------------------------------------------------------------------
// scan pass C: rescan sub-chunk seeded with h_init, y inline, fused epilogue
// (y+x*D)*silu(z) -> bf16 pair in-place over xz's xi slot. grid 1024.
// ---------------------------------------------------------------------------
__global__ __launch_bounds__(256) void k_scanC(
    const float* __restrict__ dtf, const float* __restrict__ xc,
    const float* __restrict__ dbc, float* __restrict__ xz,
    const float* __restrict__ A_log, const float* __restrict__ Dp,
    const float* __restrict__ hinit)
{
    int bx = blockIdx.x;
    int b    = bx >> 5;
    int half = (bx >> 4) & 1;
    int c    = bx & 15;
    int d = (half << 8) + threadIdx.x;

    float A2[DS], h[DS];
    const float* hp = hinit + ((size_t)(c * 32 + b) * 512 + d) * DS;
#pragma unroll
    for (int s = 0; s < DS; s++) {
        A2[s] = -__expf(A_log[d * DS + s]) * LOG2E;
        h[s] = hp[s];
    }
    float Dv = Dp[d];

    __shared__ float BC[SCT][32];
    for (int f = threadIdx.x; f < SCT * 32; f += 256) {
        int tt = f >> 5, jj = f & 31;
        BC[tt][jj] = dbc[((size_t)(c * SCT + tt) * 32 + b) * 48 + 16 + jj];
    }
    __syncthreads();

    for (int tt = 0; tt < SCT; tt++) {
        size_t row = (size_t)(c * SCT + tt) * 32 + b;
        size_t idx = row * DI + d;
        float dt = dtf[idx];
        float x  = xc[idx];
        float z  = xz[(row << 10) + 512 + d];
        float dtx = dt * x;
        float y = 0.f;
#pragma unroll
        for (int s = 0; s < DS; s++) {
            float dA = exp2f(dt * A2[s]);
            h[s] = fmaf(dA, h[s], dtx * BC[tt][s]);
            y = fmaf(h[s], BC[tt][16 + s], y);
        }
        float yact = (y + x * Dv) * (z / (1.f + __expf(-z)));
        ((unsigned*)xz)[(row << 10) + d] = packpair(yact);
    }
}

// ---------------------------------------------------------------------------
// mean accumulate / head
// ---------------------------------------------------------------------------
__global__ __launch_bounds__(256) void k_meanacc(
    const float* __restrict__ mo, float* __restrict__ meanacc, int first)
{
    int b = blockIdx.x;
    int m = threadIdx.x;
    float s = 0.f;
    for (int tl = 0; tl < CH; tl++)
        s += mo[((size_t)tl * 32 + b) * 256 + m];
    if (first) meanacc[b * 256 + m] = s;
    else       meanacc[b * 256 + m] += s;
}

__global__ __launch_bounds__(128) void k_head(
    const float* __restrict__ meanacc, const float* __restrict__ xst,
    const float* __restrict__ h1w, const float* __restrict__ h1b,
    const float* __restrict__ h2w, const float* __restrict__ h2b,
    float* __restrict__ out)
{
    int b = blockIdx.x;
    int j = threadIdx.x;
    const float* wr = h1w + j * 261;
    const float* mr = meanacc + b * 256;
    float s = h1b[j];
    for (int k = 0; k < 256; k++) s = fmaf(mr[k] * (1.f / 1024.f), wr[k], s);
    for (int k = 0; k < 5; k++) s = fmaf(xst[b * 5 + k], wr[256 + k], s);
    float e = (s > 0.f) ? s : expm1f(s);

    __shared__ float sb[128];
    sb[j] = e * h2w[j];
    __syncthreads();
    for (int o = 64; o > 0; o >>= 1) {
        if (j < o) sb[j] += sb[j + o];
        __syncthreads();
    }
    if (j == 0) out[b] = sb[0] + h2b[0];
}

// ---------------------------------------------------------------------------
// host side
// ---------------------------------------------------------------------------
static void run_mamba_chunk(hipStream_t stream, const unsigned* xinp, void* const* P,
                            const unsigned* winp, const unsigned* woutp, int out_pairs,
                            float* xzc, float* xcc, float* dbcc, float* dtc,
                            float* moc, float* hendb, float* sumdtb, float* halo,
                            float* hstate, int t0)
{
    const float* cw     = (const float*)P[1];
    const float* cb     = (const float*)P[2];
    const float* xpw    = (const float*)P[3];
    const float* dtw    = (const float*)P[4];
    const float* dtbias = (const float*)P[5];
    const float* Alog   = (const float*)P[6];
    const float* Dp     = (const float*)P[7];
    int first = (t0 == 0);

    k_gmfma<0, false><<<dim3(RC / 128, 1024 / 128), 256, 0, stream>>>(
        xinp, 256, winp, nullptr, xzc, 1024, 256);
    k_cxd<<<RC / 8, 256, 0, stream>>>(xzc, halo, cw, cb, xpw, dtw, dtbias,
                                      xcc, dbcc, dtc, t0);
    k_halo<<<3 * 32 * 512 / 256, 256, 0, stream>>>(xzc, halo);
    k_scanA<<<32 * 2 * NSC, 256, 0, stream>>>(dtc, xcc, dbcc, Alog, hendb, sumdtb);
    k_scanB<<<32 * 512 * DS / 256, 256, 0, stream>>>(sumdtb, hendb, Alog, hstate, first);
    k_scanC<<<32 * 2 * NSC, 256, 0, stream>>>(dtc, xcc, dbcc, xzc, Alog, Dp, hendb);
    if (out_pairs)
        k_gmfma<1, false><<<dim3(RC / 128, 256 / 128), 256, 0, stream>>>(
            (const unsigned*)xzc, 1024, woutp, nullptr, moc, 256, 512);
    else
        k_gmfma<0, false><<<dim3(RC / 128, 256 / 128), 256, 0, stream>>>(
            (const unsigned*)xzc, 1024, woutp, nullptr, moc, 256, 512);
}

extern "C" void kernel_launch(void* const* d_in, const int* in_sizes, int n_in,
                              void* d_out, int out_size, void* d_ws, size_t ws_size,
                              hipStream_t stream)
{
    const float* xseq = (const float*)d_in[0];
    const float* xst  = (const float*)d_in[1];
    const float* p1w  = (const float*)d_in[2];
    const float* p1b  = (const float*)d_in[3];
    const float* ln1g = (const float*)d_in[4];
    const float* ln1b = (const float*)d_in[5];
    const float* p2w  = (const float*)d_in[6];
    const float* p2b  = (const float*)d_in[7];
    const float* ln2g = (const float*)d_in[8];
    const float* ln2b = (const float*)d_in[9];
    const float* h1w  = (const float*)d_in[10];
    const float* h1b  = (const float*)d_in[11];
    const float* h2w  = (const float*)d_in[12];
    const float* h2b  = (const float*)d_in[13];

    float* ws = (float*)d_ws;
    float*    xzc    = ws;                                  // RC*1024 f32
    float*    xcc    = xzc  + (size_t)RC * 1024;            // RC*512
    float*    dtc    = xcc  + (size_t)RC * 512;             // RC*512
    float*    dbcc   = dtc  + (size_t)RC * 512;             // RC*48
    float*    moc    = dbcc + (size_t)RC * 48;              // RC*256
    unsigned* x1p    = (unsigned*)(moc + (size_t)RC * 256); // RC*256 pairs
    // hend aliases moc+x1p (4.19M floats) — both dead during scan phase
    float*    hendb  = moc;                                 // NSC*32*512*DS
    float*    sumdtb = (float*)(x1p + (size_t)RC * 256);    // NSC*32*512
    float*    halo1  = sumdtb + NSC * 32 * 512;             // 3*32*512
    float*    halo2  = halo1 + 3 * 32 * 512;
    float*    hs1    = halo2 + 3 * 32 * 512;                // 32*512*16
    float*    hs2    = hs1  + 32 * 512 * DS;
    float*    macc   = hs2  + 32 * 512 * DS;                // 32*256
    unsigned* wm1i   = (unsigned*)(macc + 32 * 256);        // 1024*256
    unsigned* wm1o   = wm1i + 262144;                       // 256*512
    unsigned* wm2i   = wm1o + 131072;
    unsigned* wm2o   = wm2i + 262144;
    unsigned* wp2    = wm2o + 131072;                       // 256*256
    size_t need = (size_t)((float*)(wp2 + 65536) - ws) * sizeof(float);
    if (ws_size < need) return;   // tripwire: fail cleanly, don't fault

    // weight bf16-pair conversion (once per launch)
    k_wcvt<<<262144 / 256, 256, 0, stream>>>((const float*)d_in[14], wm1i, 262144);
    k_wcvt<<<131072 / 256, 256, 0, stream>>>((const float*)d_in[22], wm1o, 131072);
    k_wcvt<<<262144 / 256, 256, 0, stream>>>((const float*)d_in[23], wm2i, 262144);
    k_wcvt<<<131072 / 256, 256, 0, stream>>>((const float*)d_in[31], wm2o, 131072);
    k_wcvt<<<65536 / 256, 256, 0, stream>>>(p2w, wp2, 65536);

    for (int c = 0; c < NCH; c++) {
        int t0 = c * CH;
        int first = (c == 0);

        k_p1_ln<<<RC, 256, 0, stream>>>(xseq, p1w, p1b, ln1g, ln1b, x1p, t0);

        // mamba 1 (params d_in[14..22]); out_proj emits pairs for p2
        run_mamba_chunk(stream, x1p, d_in + 14, wm1i, wm1o, 1,
                        xzc, xcc, dbcc, dtc, moc, hendb, sumdtb, halo1, hs1, t0);

        // p2 + LN2
        k_gmfma<0, true><<<dim3(RC / 128, 256 / 128), 256, 0, stream>>>(
            (const unsigned*)moc, 256, wp2, p2b, xzc, 256, 256);
        k_ln<<<RC, 256, 0, stream>>>(xzc, ln2g, ln2b, x1p);

        // mamba 2 (params d_in[23..31]); out_proj emits f32 for meanacc
        run_mamba_chunk(stream, x1p, d_in + 23, wm2i, wm2o, 0,
                        xzc, xcc, dbcc, dtc, moc, hendb, sumdtb, halo2, hs2, t0);

        k_meanacc<<<NB, 256, 0, stream>>>(moc, macc, first);
    }

    k_head<<<NB, 128, 0, stream>>>(macc, xst, h1w, h1b, h2w, h2b, (float*)d_out);
}

// Round 7
// 1589.099 us; speedup vs baseline: 1.2458x; 1.2458x over previous
//
#include <hip/hip_runtime.h>
#include <math.h>

#define NB 32
#define L  1024
#define CH 256                 // timesteps per chunk
#define NCH (L / CH)           // 4 chunks
#define RC (NB * CH)           // 8192 rows per chunk
#define DM 256
#define DI 512
#define DS 16
#define SCT 16                 // sub-chunk timesteps (scan)
#define NSC (CH / SCT)         // 16 sub-chunks
#define LOG2E 1.44269504f

typedef short short8 __attribute__((ext_vector_type(8)));
typedef float f32x4 __attribute__((ext_vector_type(4)));

// bf16 split helpers: x ~= hi + lo, both bf16 (rne). pair = hi | (lo<<16).
__device__ inline unsigned f2bf_u(float x) {
    unsigned u = __float_as_uint(x);
    return (u + 0x7fffu + ((u >> 16) & 1u)) >> 16;
}
__device__ inline unsigned packpair(float v) {
    unsigned h = f2bf_u(v);
    float hf = __uint_as_float(h << 16);
    unsigned l = f2bf_u(v - hf);
    return h | (l << 16);
}

// Layout: per-chunk activations use (t_local, b, feat): row r = t_local*32 + b.

// ---------------------------------------------------------------------------
// p1 (K=4) + bias + LayerNorm; emits bf16 hi/lo pairs for the MFMA in_proj.
// ---------------------------------------------------------------------------
__global__ __launch_bounds__(256) void k_p1_ln(
    const float* __restrict__ xseq, const float* __restrict__ w,
    const float* __restrict__ bias, const float* __restrict__ g,
    const float* __restrict__ bb, unsigned* __restrict__ out, int t0)
{
    int r  = blockIdx.x;
    int b  = r & 31;
    int tl = r >> 5;
    int m  = threadIdx.x;
    const float* xr = xseq + ((size_t)b * L + t0 + tl) * 4;
    float x0 = xr[0], x1 = xr[1], x2 = xr[2], x3 = xr[3];
    const float* wr = w + m * 4;
    float v = bias[m] + x0 * wr[0] + x1 * wr[1] + x2 * wr[2] + x3 * wr[3];

    __shared__ float s1[4], s2[4];
    float a = v, bq = v * v;
    for (int o = 32; o > 0; o >>= 1) { a += __shfl_down(a, o); bq += __shfl_down(bq, o); }
    int wid = m >> 6, lane = m & 63;
    if (lane == 0) { s1[wid] = a; s2[wid] = bq; }
    __syncthreads();
    if (m == 0) {
        s1[0] = s1[0] + s1[1] + s1[2] + s1[3];
        s2[0] = s2[0] + s2[1] + s2[2] + s2[3];
    }
    __syncthreads();
    float mu  = s1[0] * (1.f / 256.f);
    float var = s2[0] * (1.f / 256.f) - mu * mu;
    float o2 = (v - mu) * rsqrtf(var + 1e-5f) * g[m] + bb[m];
    out[(size_t)r * 256 + m] = packpair(o2);
}

// ---------------------------------------------------------------------------
// LayerNorm over 256; fp32 in, bf16-pair out.
// ---------------------------------------------------------------------------
__global__ __launch_bounds__(256) void k_ln(
    const float* __restrict__ in, const float* __restrict__ g,
    const float* __restrict__ bb, unsigned* __restrict__ out)
{
    int r = blockIdx.x;
    int m = threadIdx.x;
    float v = in[(size_t)r * 256 + m];

    __shared__ float s1[4], s2[4];
    float a = v, bq = v * v;
    for (int o = 32; o > 0; o >>= 1) { a += __shfl_down(a, o); bq += __shfl_down(bq, o); }
    int wid = m >> 6, lane = m & 63;
    if (lane == 0) { s1[wid] = a; s2[wid] = bq; }
    __syncthreads();
    if (m == 0) {
        s1[0] = s1[0] + s1[1] + s1[2] + s1[3];
        s2[0] = s2[0] + s2[1] + s2[2] + s2[3];
    }
    __syncthreads();
    float mu  = s1[0] * (1.f / 256.f);
    float var = s2[0] * (1.f / 256.f) - mu * mu;
    float o2 = (v - mu) * rsqrtf(var + 1e-5f) * g[m] + bb[m];
    out[(size_t)r * 256 + m] = packpair(o2);
}

__global__ __launch_bounds__(256) void k_wcvt(
    const float* __restrict__ w, unsigned* __restrict__ o, int n)
{
    int i = blockIdx.x * 256 + threadIdx.x;
    if (i < n) o[i] = packpair(w[i]);
}

// ---------------------------------------------------------------------------
// split-bf16 MFMA GEMM (3-term): C[M,N] = A[M,K]*W[N,K]^T (+bias).
// 128x128 tile, BK=32, 4 waves x 64x64 quadrant of 4x4 16x16x32 frags.
// ---------------------------------------------------------------------------
template <int OUTK, bool BIAS>
__global__ __launch_bounds__(256) void k_gmfma(
    const unsigned* __restrict__ Ap, int lda,
    const unsigned* __restrict__ Wp,
    const float* __restrict__ bias, void* __restrict__ Cv,
    int N, int K)
{
    __shared__ unsigned short Ah[128 * 40], Al[128 * 40];
    __shared__ unsigned short Wh[128 * 40], Wl[128 * 40];

    int tid = threadIdx.x;
    int wv = tid >> 6, ln = tid & 63;
    int wr = wv >> 1, wc = wv & 1;
    int m0 = blockIdx.x * 128, n0 = blockIdx.y * 128;
    int sr = tid >> 1, sk = (tid & 1) << 4;
    int frow = ln & 15, fk = (ln >> 4) << 3;

    f32x4 acc[4][4] = {};

    for (int k0 = 0; k0 < K; k0 += 32) {
        const unsigned* ap = Ap + (size_t)(m0 + sr) * lda + k0 + sk;
        const unsigned* wp = Wp + (size_t)(n0 + sr) * K + k0 + sk;
        uint4 qa[4], qw[4];
#pragma unroll
        for (int i = 0; i < 4; i++) qa[i] = *(const uint4*)(ap + i * 4);
#pragma unroll
        for (int i = 0; i < 4; i++) qw[i] = *(const uint4*)(wp + i * 4);

        __syncthreads();

        unsigned short th[16], tl[16];
#pragma unroll
        for (int i = 0; i < 4; i++) {
            th[i*4+0] = (unsigned short)qa[i].x; tl[i*4+0] = (unsigned short)(qa[i].x >> 16);
            th[i*4+1] = (unsigned short)qa[i].y; tl[i*4+1] = (unsigned short)(qa[i].y >> 16);
            th[i*4+2] = (unsigned short)qa[i].z; tl[i*4+2] = (unsigned short)(qa[i].z >> 16);
            th[i*4+3] = (unsigned short)qa[i].w; tl[i*4+3] = (unsigned short)(qa[i].w >> 16);
        }
        *(short8*)&Ah[sr * 40 + sk]     = *(short8*)&th[0];
        *(short8*)&Ah[sr * 40 + sk + 8] = *(short8*)&th[8];
        *(short8*)&Al[sr * 40 + sk]     = *(short8*)&tl[0];
        *(short8*)&Al[sr * 40 + sk + 8] = *(short8*)&tl[8];
#pragma unroll
        for (int i = 0; i < 4; i++) {
            th[i*4+0] = (unsigned short)qw[i].x; tl[i*4+0] = (unsigned short)(qw[i].x >> 16);
            th[i*4+1] = (unsigned short)qw[i].y; tl[i*4+1] = (unsigned short)(qw[i].y >> 16);
            th[i*4+2] = (unsigned short)qw[i].z; tl[i*4+2] = (unsigned short)(qw[i].z >> 16);
            th[i*4+3] = (unsigned short)qw[i].w; tl[i*4+3] = (unsigned short)(qw[i].w >> 16);
        }
        *(short8*)&Wh[sr * 40 + sk]     = *(short8*)&th[0];
        *(short8*)&Wh[sr * 40 + sk + 8] = *(short8*)&th[8];
        *(short8*)&Wl[sr * 40 + sk]     = *(short8*)&tl[0];
        *(short8*)&Wl[sr * 40 + sk + 8] = *(short8*)&tl[8];

        __syncthreads();

        short8 afh[4], afl[4], wfh[4], wfl[4];
#pragma unroll
        for (int g = 0; g < 4; g++) {
            int ra = (wr * 64 + g * 16 + frow) * 40 + fk;
            int rw = (wc * 64 + g * 16 + frow) * 40 + fk;
            afh[g] = *(const short8*)&Ah[ra];
            afl[g] = *(const short8*)&Al[ra];
            wfh[g] = *(const short8*)&Wh[rw];
            wfl[g] = *(const short8*)&Wl[rw];
        }
#pragma unroll
        for (int mg = 0; mg < 4; mg++)
#pragma unroll
            for (int ng = 0; ng < 4; ng++) {
                acc[mg][ng] = __builtin_amdgcn_mfma_f32_16x16x32_bf16(afh[mg], wfh[ng], acc[mg][ng], 0, 0, 0);
                acc[mg][ng] = __builtin_amdgcn_mfma_f32_16x16x32_bf16(afh[mg], wfl[ng], acc[mg][ng], 0, 0, 0);
                acc[mg][ng] = __builtin_amdgcn_mfma_f32_16x16x32_bf16(afl[mg], wfh[ng], acc[mg][ng], 0, 0, 0);
            }
    }

    // C layout: col=lane&15, row=(lane>>4)*4+reg  [verified m89]
#pragma unroll
    for (int ng = 0; ng < 4; ng++) {
        int col = n0 + wc * 64 + ng * 16 + frow;
        float bv = BIAS ? bias[col] : 0.f;
#pragma unroll
        for (int mg = 0; mg < 4; mg++)
#pragma unroll
            for (int r = 0; r < 4; r++) {
                int row = m0 + wr * 64 + mg * 16 + (ln >> 4) * 4 + r;
                float v = acc[mg][ng][r] + bv;
                if (OUTK == 0) ((float*)Cv)[(size_t)row * N + col] = v;
                else           ((unsigned*)Cv)[(size_t)row * N + col] = packpair(v);
            }
    }
}

// ---------------------------------------------------------------------------
// fp32 tiled GEMM (xproj, N=48): BM=BN=64, BK=16, 4x4/thread.
// ---------------------------------------------------------------------------
template <bool BIAS>
__global__ __launch_bounds__(256) void k_gemm(
    const float* __restrict__ A, const float* __restrict__ W,
    const float* __restrict__ bias, float* __restrict__ C,
    int M, int N, int K)
{
    const int BM = 64, BN = 64, BK = 16;
    __shared__ float As[BK][BM];
    __shared__ float Ws[BK][BN];

    int m0  = blockIdx.x * BM;
    int n0  = blockIdx.y * BN;
    int tid = threadIdx.x;
    int tx  = tid & 15, ty = tid >> 4;
    int lr  = tid >> 2;
    int lc  = (tid & 3) * 4;

    float acc[4][4] = {};

    for (int k0 = 0; k0 < K; k0 += BK) {
        float4 av = *(const float4*)(A + (size_t)(m0 + lr) * K + k0 + lc);
        As[lc + 0][lr] = av.x; As[lc + 1][lr] = av.y;
        As[lc + 2][lr] = av.z; As[lc + 3][lr] = av.w;
        float4 wv = make_float4(0.f, 0.f, 0.f, 0.f);
        if (n0 + lr < N) wv = *(const float4*)(W + (size_t)(n0 + lr) * K + k0 + lc);
        Ws[lc + 0][lr] = wv.x; Ws[lc + 1][lr] = wv.y;
        Ws[lc + 2][lr] = wv.z; Ws[lc + 3][lr] = wv.w;
        __syncthreads();
#pragma unroll
        for (int k = 0; k < BK; k++) {
            float a[4], bv[4];
            *(float4*)a  = *(const float4*)&As[k][ty * 4];
            *(float4*)bv = *(const float4*)&Ws[k][tx * 4];
#pragma unroll
            for (int i = 0; i < 4; i++)
#pragma unroll
                for (int j = 0; j < 4; j++)
                    acc[i][j] = fmaf(a[i], bv[j], acc[i][j]);
        }
        __syncthreads();
    }

    int n = n0 + tx * 4;
    float4 bv = make_float4(0.f, 0.f, 0.f, 0.f);
    if (BIAS && n < N) bv = *(const float4*)(bias + n);
#pragma unroll
    for (int i = 0; i < 4; i++) {
        if (n < N) {
            float4 v = make_float4(acc[i][0] + bv.x, acc[i][1] + bv.y,
                                   acc[i][2] + bv.z, acc[i][3] + bv.w);
            *(float4*)(C + (size_t)(m0 + ty * 4 + i) * N + n) = v;
        }
    }
}

// ---------------------------------------------------------------------------
// depthwise causal conv1d (k=4) + SiLU, chunked with halo [3][32][512].
// ---------------------------------------------------------------------------
__global__ __launch_bounds__(256) void k_conv(
    const float* __restrict__ xz, const float* __restrict__ halo,
    const float* __restrict__ cw, const float* __restrict__ cb,
    float* __restrict__ xc, int t0)
{
    size_t idx = (size_t)blockIdx.x * 256 + threadIdx.x;   // over RC*512
    int d  = (int)(idx & (DI - 1));
    int r  = (int)(idx >> 9);
    int b  = r & 31;
    int tl = r >> 5;

    float4 wv = *(const float4*)(cw + d * 4);
    float wk[4] = { wv.x, wv.y, wv.z, wv.w };
    float acc = cb[d];

    if (tl >= 3) {
        const float* base = xz + ((size_t)(tl - 3) * 32 + b) * 1024 + d;
#pragma unroll
        for (int k = 0; k < 4; k++) acc = fmaf(wk[k], base[(size_t)k * 32 * 1024], acc);
    } else {
#pragma unroll
        for (int k = 0; k < 4; k++) {
            int ts = t0 + tl - 3 + k;
            float v;
            if (ts < 0) continue;
            else if (ts >= t0) v = xz[((size_t)(tl - 3 + k) * 32 + b) * 1024 + d];
            else v = halo[((size_t)(tl - 3 + k + 3) * 32 + b) * 512 + d];
            acc = fmaf(wk[k], v, acc);
        }
    }
    xc[idx] = acc / (1.f + __expf(-acc));      // silu
}

__global__ __launch_bounds__(256) void k_halo(
    const float* __restrict__ xz, float* __restrict__ halo)
{
    int idx = blockIdx.x * 256 + threadIdx.x;  // over 3*32*512
    int d = idx & 511;
    int b = (idx >> 9) & 31;
    int s = idx >> 14;
    halo[idx] = xz[(((size_t)(CH - 3 + s) * 32 + b) << 10) + d];
}

// ---------------------------------------------------------------------------
// dt projection (K=16) + softplus
// ---------------------------------------------------------------------------
__global__ __launch_bounds__(256) void k_dt(
    const float* __restrict__ dbc, const float* __restrict__ dtw,
    const float* __restrict__ dtb, float* __restrict__ dtf)
{
    size_t idx = (size_t)blockIdx.x * 256 + threadIdx.x;   // over RC*512
    int d = (int)(idx & (DI - 1));
    size_t r = idx >> 9;
    const float* dr = dbc + r * 48;
    const float* w  = dtw + d * 16;
    float s = dtb[d];
#pragma unroll
    for (int k = 0; k < 16; k++) s = fmaf(dr[k], w[k], s);
    dtf[idx] = (s > 20.f) ? s : log1pf(expf(s));
}

// ---------------------------------------------------------------------------
// scan pass A: local scan per sub-chunk (h=0). Writes ONLY hend + sumdt.
// grid: b(32) x half(2) x subchunk(16) = 1024 blocks.
// ---------------------------------------------------------------------------
__global__ __launch_bounds__(256) void k_scanA(
    const float* __restrict__ dtf, const float* __restrict__ xc,
    const float* __restrict__ dbc, const float* __restrict__ A_log,
    float* __restrict__ hend, float* __restrict__ sumdt)
{
    int bx = blockIdx.x;
    int b    = bx >> 5;
    int half = (bx >> 4) & 1;
    int c    = bx & 15;
    int d = (half << 8) + threadIdx.x;

    float A2[DS], h[DS];
#pragma unroll
    for (int s = 0; s < DS; s++) {
        A2[s] = -__expf(A_log[d * DS + s]) * LOG2E;
        h[s] = 0.f;
    }

    __shared__ float Bs[SCT][16];
    {
        int f = threadIdx.x;           // SCT*16 = 256 exactly
        int tt = f >> 4, jj = f & 15;
        Bs[tt][jj] = dbc[((size_t)(c * SCT + tt) * 32 + b) * 48 + 16 + jj];
    }
    __syncthreads();

    float cum = 0.f;
    for (int tt = 0; tt < SCT; tt++) {
        size_t idx = ((size_t)(c * SCT + tt) * 32 + b) * DI + d;
        float dt = dtf[idx];
        cum += dt;
        float dtx = dt * xc[idx];
#pragma unroll
        for (int s = 0; s < DS; s++) {
            float dA = exp2f(dt * A2[s]);
            h[s] = fmaf(dA, h[s], dtx * Bs[tt][s]);
        }
    }
    float* hp = hend + ((size_t)(c * 32 + b) * 512 + d) * DS;
#pragma unroll
    for (int s = 0; s < DS; s++) hp[s] = h[s];
    sumdt[((size_t)c * 32 + b) * 512 + d] = cum;
}

// ---------------------------------------------------------------------------
// scan pass B: carry across 16 sub-chunks; hend -> h_init, carry -> hs.
// ---------------------------------------------------------------------------
__global__ __launch_bounds__(256) void k_scanB(
    const float* __restrict__ sumdt, float* __restrict__ hend,
    const float* __restrict__ A_log, float* __restrict__ hs, int first)
{
    int id = blockIdx.x * 256 + threadIdx.x;   // 32*512*16 = 262144
    int s = id & 15;
    int d = (id >> 4) & 511;
    int b = id >> 13;
    float A2 = -__expf(A_log[d * DS + s]) * LOG2E;
    size_t hsi = ((size_t)(b << 9) + d) * DS + s;
    float hin = first ? 0.f : hs[hsi];
    for (int c = 0; c < NSC; c++) {
        size_t hi = ((size_t)(c * 32 + b) * 512 + d) * DS + s;
        float he = hend[hi];
        float sd = sumdt[((size_t)c * 32 + b) * 512 + d];
        hend[hi] = hin;
        hin = fmaf(exp2f(A2 * sd), hin, he);
    }
    hs[hsi] = hin;
}

// ---------------------------------------------------------------------------
// scan pass C: rescan sub-chunk seeded with h_init, y inline, fused epilogue
// (y+x*D)*silu(z) -> bf16 pair in-place over xz's xi slot. grid 1024.
// ---------------------------------------------------------------------------
__global__ __launch_bounds__(256) void k_scanC(
    const float* __restrict__ dtf, const float* __restrict__ xc,
    const float* __restrict__ dbc, float* __restrict__ xz,
    const float* __restrict__ A_log, const float* __restrict__ Dp,
    const float* __restrict__ hinit)
{
    int bx = blockIdx.x;
    int b    = bx >> 5;
    int half = (bx >> 4) & 1;
    int c    = bx & 15;
    int d = (half << 8) + threadIdx.x;

    float A2[DS], h[DS];
    const float* hp = hinit + ((size_t)(c * 32 + b) * 512 + d) * DS;
#pragma unroll
    for (int s = 0; s < DS; s++) {
        A2[s] = -__expf(A_log[d * DS + s]) * LOG2E;
        h[s] = hp[s];
    }
    float Dv = Dp[d];

    __shared__ float BC[SCT][32];
    for (int f = threadIdx.x; f < SCT * 32; f += 256) {
        int tt = f >> 5, jj = f & 31;
        BC[tt][jj] = dbc[((size_t)(c * SCT + tt) * 32 + b) * 48 + 16 + jj];
    }
    __syncthreads();

    for (int tt = 0; tt < SCT; tt++) {
        size_t row = (size_t)(c * SCT + tt) * 32 + b;
        size_t idx = row * DI + d;
        float dt = dtf[idx];
        float x  = xc[idx];
        float z  = xz[(row << 10) + 512 + d];
        float dtx = dt * x;
        float y = 0.f;
#pragma unroll
        for (int s = 0; s < DS; s++) {
            float dA = exp2f(dt * A2[s]);
            h[s] = fmaf(dA, h[s], dtx * BC[tt][s]);
            y = fmaf(h[s], BC[tt][16 + s], y);
        }
        float yact = (y + x * Dv) * (z / (1.f + __expf(-z)));
        ((unsigned*)xz)[(row << 10) + d] = packpair(yact);
    }
}

// ---------------------------------------------------------------------------
// mean accumulate / head
// ---------------------------------------------------------------------------
__global__ __launch_bounds__(256) void k_meanacc(
    const float* __restrict__ mo, float* __restrict__ meanacc, int first)
{
    int b = blockIdx.x;
    int m = threadIdx.x;
    float s = 0.f;
    for (int tl = 0; tl < CH; tl++)
        s += mo[((size_t)tl * 32 + b) * 256 + m];
    if (first) meanacc[b * 256 + m] = s;
    else       meanacc[b * 256 + m] += s;
}

__global__ __launch_bounds__(128) void k_head(
    const float* __restrict__ meanacc, const float* __restrict__ xst,
    const float* __restrict__ h1w, const float* __restrict__ h1b,
    const float* __restrict__ h2w, const float* __restrict__ h2b,
    float* __restrict__ out)
{
    int b = blockIdx.x;
    int j = threadIdx.x;
    const float* wr = h1w + j * 261;
    const float* mr = meanacc + b * 256;
    float s = h1b[j];
    for (int k = 0; k < 256; k++) s = fmaf(mr[k] * (1.f / 1024.f), wr[k], s);
    for (int k = 0; k < 5; k++) s = fmaf(xst[b * 5 + k], wr[256 + k], s);
    float e = (s > 0.f) ? s : expm1f(s);

    __shared__ float sb[128];
    sb[j] = e * h2w[j];
    __syncthreads();
    for (int o = 64; o > 0; o >>= 1) {
        if (j < o) sb[j] += sb[j + o];
        __syncthreads();
    }
    if (j == 0) out[b] = sb[0] + h2b[0];
}

// ---------------------------------------------------------------------------
// host side
// ---------------------------------------------------------------------------
static void run_mamba_chunk(hipStream_t stream, const unsigned* xinp, void* const* P,
                            const unsigned* winp, const unsigned* woutp, int out_pairs,
                            float* xzc, float* xcc, float* dbcc, float* dtc,
                            float* moc, float* hendb, float* sumdtb, float* halo,
                            float* hstate, int t0)
{
    const float* cw     = (const float*)P[1];
    const float* cb     = (const float*)P[2];
    const float* xpw    = (const float*)P[3];
    const float* dtw    = (const float*)P[4];
    const float* dtbias = (const float*)P[5];
    const float* Alog   = (const float*)P[6];
    const float* Dp     = (const float*)P[7];
    int first = (t0 == 0);

    k_gmfma<0, false><<<dim3(RC / 128, 1024 / 128), 256, 0, stream>>>(
        xinp, 256, winp, nullptr, xzc, 1024, 256);
    k_conv<<<RC * DI / 256, 256, 0, stream>>>(xzc, halo, cw, cb, xcc, t0);
    k_halo<<<3 * 32 * 512 / 256, 256, 0, stream>>>(xzc, halo);
    k_gemm<false><<<dim3(RC / 64, 1), 256, 0, stream>>>(
        xcc, xpw, nullptr, dbcc, RC, 48, 512);
    k_dt<<<RC * DI / 256, 256, 0, stream>>>(dbcc, dtw, dtbias, dtc);
    k_scanA<<<32 * 2 * NSC, 256, 0, stream>>>(dtc, xcc, dbcc, Alog, hendb, sumdtb);
    k_scanB<<<32 * 512 * DS / 256, 256, 0, stream>>>(sumdtb, hendb, Alog, hstate, first);
    k_scanC<<<32 * 2 * NSC, 256, 0, stream>>>(dtc, xcc, dbcc, xzc, Alog, Dp, hendb);
    if (out_pairs)
        k_gmfma<1, false><<<dim3(RC / 128, 256 / 128), 256, 0, stream>>>(
            (const unsigned*)xzc, 1024, woutp, nullptr, moc, 256, 512);
    else
        k_gmfma<0, false><<<dim3(RC / 128, 256 / 128), 256, 0, stream>>>(
            (const unsigned*)xzc, 1024, woutp, nullptr, moc, 256, 512);
}

extern "C" void kernel_launch(void* const* d_in, const int* in_sizes, int n_in,
                              void* d_out, int out_size, void* d_ws, size_t ws_size,
                              hipStream_t stream)
{
    const float* xseq = (const float*)d_in[0];
    const float* xst  = (const float*)d_in[1];
    const float* p1w  = (const float*)d_in[2];
    const float* p1b  = (const float*)d_in[3];
    const float* ln1g = (const float*)d_in[4];
    const float* ln1b = (const float*)d_in[5];
    const float* p2w  = (const float*)d_in[6];
    const float* p2b  = (const float*)d_in[7];
    const float* ln2g = (const float*)d_in[8];
    const float* ln2b = (const float*)d_in[9];
    const float* h1w  = (const float*)d_in[10];
    const float* h1b  = (const float*)d_in[11];
    const float* h2w  = (const float*)d_in[12];
    const float* h2b  = (const float*)d_in[13];

    float* ws = (float*)d_ws;
    float*    xzc    = ws;                                  // RC*1024 f32
    float*    xcc    = xzc  + (size_t)RC * 1024;            // RC*512
    float*    dtc    = xcc  + (size_t)RC * 512;             // RC*512
    float*    dbcc   = dtc  + (size_t)RC * 512;             // RC*48
    float*    moc    = dbcc + (size_t)RC * 48;              // RC*256
    unsigned* x1p    = (unsigned*)(moc + (size_t)RC * 256); // RC*256 pairs
    // hend aliases moc∪x1p (4.19M floats) — both dead during scan phase
    float*    hendb  = moc;                                 // NSC*32*512*DS
    float*    sumdtb = (float*)(x1p + (size_t)RC * 256);    // NSC*32*512
    float*    halo1  = sumdtb + NSC * 32 * 512;             // 3*32*512
    float*    halo2  = halo1 + 3 * 32 * 512;
    float*    hs1    = halo2 + 3 * 32 * 512;                // 32*512*16
    float*    hs2    = hs1  + 32 * 512 * DS;
    float*    macc   = hs2  + 32 * 512 * DS;                // 32*256
    unsigned* wm1i   = (unsigned*)(macc + 32 * 256);        // 1024*256
    unsigned* wm1o   = wm1i + 262144;                       // 256*512
    unsigned* wm2i   = wm1o + 131072;
    unsigned* wm2o   = wm2i + 262144;
    unsigned* wp2    = wm2o + 131072;                       // 256*256
    size_t need = (size_t)((float*)(wp2 + 65536) - ws) * sizeof(float);
    if (ws_size < need) return;   // tripwire: fail cleanly, don't fault

    // weight bf16-pair conversion (once per launch)
    k_wcvt<<<262144 / 256, 256, 0, stream>>>((const float*)d_in[14], wm1i, 262144);
    k_wcvt<<<131072 / 256, 256, 0, stream>>>((const float*)d_in[22], wm1o, 131072);
    k_wcvt<<<262144 / 256, 256, 0, stream>>>((const float*)d_in[23], wm2i, 262144);
    k_wcvt<<<131072 / 256, 256, 0, stream>>>((const float*)d_in[31], wm2o, 131072);
    k_wcvt<<<65536 / 256, 256, 0, stream>>>(p2w, wp2, 65536);

    for (int c = 0; c < NCH; c++) {
        int t0 = c * CH;
        int first = (c == 0);

        k_p1_ln<<<RC, 256, 0, stream>>>(xseq, p1w, p1b, ln1g, ln1b, x1p, t0);

        // mamba 1 (params d_in[14..22]); out_proj emits pairs for p2
        run_mamba_chunk(stream, x1p, d_in + 14, wm1i, wm1o, 1,
                        xzc, xcc, dbcc, dtc, moc, hendb, sumdtb, halo1, hs1, t0);

        // p2 + LN2
        k_gmfma<0, true><<<dim3(RC / 128, 256 / 128), 256, 0, stream>>>(
            (const unsigned*)moc, 256, wp2, p2b, xzc, 256, 256);
        k_ln<<<RC, 256, 0, stream>>>(xzc, ln2g, ln2b, x1p);

        // mamba 2 (params d_in[23..31]); out_proj emits f32 for meanacc
        run_mamba_chunk(stream, x1p, d_in + 23, wm2i, wm2o, 0,
                        xzc, xcc, dbcc, dtc, moc, hendb, sumdtb, halo2, hs2, t0);

        k_meanacc<<<NB, 256, 0, stream>>>(moc, macc, first);
    }

    k_head<<<NB, 128, 0, stream>>>(macc, xst, h1w, h1b, h2w, h2b, (float*)d_out);
}